// Round 7
// baseline (4872.594 us; speedup 1.0000x reference)
//
#include <hip/hip_runtime.h>
#include <math.h>

// ChainedGP v7: v6 + (1) hierarchical XCD-aware grid barrier (release fence
// per XCD instead of per block — v6 measured ~43us/barrier from 256 wbl2/inv
// per barrier), (2) wave0 shuffle-register 64x64 Cholesky (no __syncthreads),
// (3) phase-3 level-0 fused (task-local both GEMMs).
#define NN 16384
#define MM 2048
#define DD 8
#define NB 32                     // MM/64
#define GRIDN 256                 // factor kernel grid (co-resident, 1/CU)
#define SZB ((size_t)16777216)    // 2048*2048*4 bytes

constexpr float HLOG2PI = 0.91893853320467274178f;

using short8  = __attribute__((ext_vector_type(8))) short;
using float4v = __attribute__((ext_vector_type(4))) float;

__device__ __forceinline__ float4v f4zero(){ float4v v; v[0]=0.f; v[1]=0.f; v[2]=0.f; v[3]=0.f; return v; }

__device__ __forceinline__ void bfsplit(float v, short& h, short& lo){
  unsigned b = __float_as_uint(v);
  h = (short)(b >> 16);
  float hf = __uint_as_float(b & 0xFFFF0000u);
  lo = (short)(__float_as_uint(v - hf) >> 16);
}
__device__ __forceinline__ float bf2f(short s){
  return __uint_as_float(((unsigned)(unsigned short)s) << 16);
}
__device__ __forceinline__ float4v mfma3(short8 ah, short8 al, short8 bh, short8 bl, float4v c){
  c = __builtin_amdgcn_mfma_f32_16x16x32_bf16(ah, bh, c, 0, 0, 0);
  c = __builtin_amdgcn_mfma_f32_16x16x32_bf16(ah, bl, c, 0, 0, 0);
  c = __builtin_amdgcn_mfma_f32_16x16x32_bf16(al, bh, c, 0, 0, 0);
  return c;
}

// ---- barrier word layout inside `bar` (all zeroed per launch) ----
// lcnt[xcc]  = bar + xcc*32          (one 128B line per XCD)
// lflag[xcc] = bar + 512 + xcc*32
// gcnt       = bar + 1024
// gflag      = bar + 1056
// cnt0/flag0 = bar + 1088 / 1120     (bootstrap barrier)
// census[xcc]= bar + 1152 + xcc*32

// bootstrap barrier (v6-style: full fences per block; used once for census)
__device__ __forceinline__ void gbar0(int* cnt, int* flag, int& gen){
  __syncthreads();
  if (threadIdx.x == 0){
    ++gen;
    __builtin_amdgcn_fence(__ATOMIC_RELEASE, "agent");
    int old = __hip_atomic_fetch_add(cnt, 1, __ATOMIC_RELAXED, __HIP_MEMORY_SCOPE_AGENT);
    if (old == gen*GRIDN - 1){
      __builtin_amdgcn_fence(__ATOMIC_ACQ_REL, "agent");
      __hip_atomic_store(flag, gen, __ATOMIC_RELAXED, __HIP_MEMORY_SCOPE_AGENT);
    } else {
      while (__hip_atomic_load(flag, __ATOMIC_RELAXED, __HIP_MEMORY_SCOPE_AGENT) < gen)
        __builtin_amdgcn_s_sleep(8);
    }
    __builtin_amdgcn_fence(__ATOMIC_ACQUIRE, "agent");
  }
  __syncthreads();
}

// hierarchical barrier: 1 release fence per XCD (wbl2 is cache-wide for the
// shared per-XCD L2), 8-way global join, per-block acquire (own L1 + L2).
__device__ __forceinline__ void gbar_h(int* bar, int xcc, int myN, int nxcd, int& gen){
  __syncthreads();   // drains each wave's vmcnt -> block's stores are in L2
  if (threadIdx.x == 0){
    ++gen;
    int* lcnt  = bar + xcc*32;
    int* lflag = bar + 512 + xcc*32;
    int* gcnt  = bar + 1024;
    int* gflag = bar + 1056;
    int old = __hip_atomic_fetch_add(lcnt, 1, __ATOMIC_RELAXED, __HIP_MEMORY_SCOPE_AGENT);
    if (old == gen*myN - 1){
      // last arriver on this XCD: flush the XCD's L2 (covers all members' writes)
      __builtin_amdgcn_fence(__ATOMIC_RELEASE, "agent");
      int g = __hip_atomic_fetch_add(gcnt, 1, __ATOMIC_RELAXED, __HIP_MEMORY_SCOPE_AGENT);
      if (g == gen*nxcd - 1){
        __hip_atomic_store(gflag, gen, __ATOMIC_RELAXED, __HIP_MEMORY_SCOPE_AGENT);
      } else {
        while (__hip_atomic_load(gflag, __ATOMIC_RELAXED, __HIP_MEMORY_SCOPE_AGENT) < gen)
          __builtin_amdgcn_s_sleep(2);
      }
      __builtin_amdgcn_fence(__ATOMIC_ACQUIRE, "agent");
      __hip_atomic_store(lflag, gen, __ATOMIC_RELAXED, __HIP_MEMORY_SCOPE_AGENT);
    } else {
      while (__hip_atomic_load(lflag, __ATOMIC_RELAXED, __HIP_MEMORY_SCOPE_AGENT) < gen)
        __builtin_amdgcn_s_sleep(4);
      __builtin_amdgcn_fence(__ATOMIC_ACQUIRE, "agent");   // own L1 (+clean L2)
    }
  }
  __syncthreads();
}

__device__ __forceinline__ float block_reduce(float v, float* scratch){
  int lane = threadIdx.x & 63;
  int w    = threadIdx.x >> 6;
  #pragma unroll
  for (int off=32; off; off>>=1) v += __shfl_down(v, off, 64);
  __syncthreads();
  if (lane==0) scratch[w] = v;
  __syncthreads();
  float r = 0.f;
  if (threadIdx.x < 4) r = scratch[threadIdx.x];
  if (w==0){ r += __shfl_down(r, 2, 64); r += __shfl_down(r, 1, 64); }
  return r;
}

// ---- 64x64 tile helpers (LDS row stride 68 floats) ----
__device__ __forceinline__ void stage64(float (*S)[68], const float* __restrict__ g, int ld, int t){
  #pragma unroll
  for (int p=t; p<1024; p+=256)
    *(float4*)&S[p>>4][(p&15)*4] = *(const float4*)&g[(size_t)(p>>4)*ld + (p&15)*4];
}
__device__ __forceinline__ void tile_gemm_step(float acc[4][4], const float (*As)[68], const float (*Bs)[68], int tx, int ty){
  for (int k=0;k<64;++k){
    float ar[4], bc4[4];
    #pragma unroll
    for (int u=0;u<4;++u){ ar[u]=As[ty*4+u][k]; bc4[u]=Bs[k][tx*4+u]; }
    #pragma unroll
    for (int u=0;u<4;++u)
      #pragma unroll
      for (int v=0;v<4;++v) acc[u][v] += ar[u]*bc4[v];
  }
}
__device__ __forceinline__ void tile_syrk_step(float acc[4][4], const float (*P)[68], const float (*Q)[68], int tx, int ty){
  for (int k=0;k<64;++k){
    float pr[4], qc[4];
    #pragma unroll
    for (int u=0;u<4;++u){ pr[u]=P[ty*4+u][k]; qc[u]=Q[tx*4+u][k]; }
    #pragma unroll
    for (int u=0;u<4;++u)
      #pragma unroll
      for (int v=0;v<4;++v) acc[u][v] += pr[u]*qc[v];
  }
}

// wave-0 register Cholesky of a 64x64 tile staged in S (LDS).
// lane t = row t; column broadcast via shuffles — no __syncthreads, no
// cross-lane LDS hazards. Writes lkdiag[d] (lower, zero upper) and sdg[d].
__device__ __forceinline__ void factor64_reg(const float (*S)[68],
    float* __restrict__ lkd, float* __restrict__ sdg_, int d, int t){
  if (t < 64){
    float xr[64];
    #pragma unroll
    for (int c4=0;c4<16;++c4) *(float4*)&xr[c4*4] = *(const float4*)&S[t][c4*4];
    float myrp = 1.f;
    #pragma unroll
    for (int j=0;j<64;++j){
      float ajj = __shfl(xr[j], j, 64);
      float piv = sqrtf(fmaxf(ajj, 1e-20f));
      float rp  = 1.f/piv;
      float val = xr[j]*rp;
      if (t==j){ xr[j] = piv; myrp = rp; }
      else if (t>j) xr[j] = val;
      else val = 0.f;
      #pragma unroll
      for (int c=j+1;c<64;++c){
        float vc = __shfl(val, c, 64);
        if (c<=t) xr[c] -= val*vc;
      }
    }
    #pragma unroll
    for (int c=0;c<64;++c) if (c>t) xr[c] = 0.f;
    #pragma unroll
    for (int c4=0;c4<16;++c4)
      *(float4*)&lkd[d*4096 + t*64 + c4*4] = *(float4*)&xr[c4*4];
    sdg_[d*64 + t] = myrp;
  }
}

// ================= fused factorization kernel (plain launch) =================
__global__ __launch_bounds__(256) void factor_coop(
    const float* __restrict__ z,
    const float* __restrict__ qlf, const float* __restrict__ qlg,
    const float* __restrict__ qmf, const float* __restrict__ qmg,
    float* __restrict__ kuu, float* __restrict__ linv,
    float* __restrict__ wf, float* __restrict__ wg,
    float* __restrict__ af, float* __restrict__ ag,
    float* __restrict__ ptmp, float* __restrict__ lkdiag,
    float* __restrict__ sdg, int* __restrict__ bar)
{
  __shared__ float As[64][68];
  __shared__ float Bs[64][68];
  __shared__ float sd[64];
  __shared__ int binfo[2];
  const int bid = blockIdx.x, t = threadIdx.x;
  const int tx = t & 15, ty = t >> 4;

  // ---- census: group blocks by physical XCD ----
  int xcc_r;
  asm volatile("s_getreg_b32 %0, hwreg(HW_REG_XCC_ID)" : "=s"(xcc_r));
  const int xcc = xcc_r & 15;
  if (t == 0)
    __hip_atomic_fetch_add(bar + 1152 + xcc*32, 1, __ATOMIC_RELAXED, __HIP_MEMORY_SCOPE_AGENT);
  int gen0 = 0;
  gbar0(bar + 1088, bar + 1120, gen0);
  if (t == 0){
    int myN = __hip_atomic_load(bar + 1152 + xcc*32, __ATOMIC_RELAXED, __HIP_MEMORY_SCOPE_AGENT);
    int nx = 0;
    for (int i=0;i<16;++i)
      nx += (__hip_atomic_load(bar + 1152 + i*32, __ATOMIC_RELAXED, __HIP_MEMORY_SCOPE_AGENT) > 0);
    binfo[0] = myN; binfo[1] = nx;
  }
  __syncthreads();
  const int myN = binfo[0], nxcd = binfo[1];
  int gen = 0;

  // ---- phase 0: Kuu lower tiles; block 0 computes+factors diag(0) ----
  if (bid == 0){
    for (int p=t; p<128; p+=256){ int i=p>>1, h=p&1;
      *(float4*)&As[i][h*4] = *(const float4*)&z[(size_t)i*DD + h*4]; }
    __syncthreads();
    float kv[4][4];
    #pragma unroll
    for (int u=0;u<4;++u)
      #pragma unroll
      for (int v=0;v<4;++v){
        float d2=0.f;
        #pragma unroll
        for (int d=0;d<8;++d){ float df=As[ty*4+u][d]-As[tx*4+v][d]; d2+=df*df; }
        kv[u][v] = __expf(-2.f*d2) + ((ty*4+u)==(tx*4+v) ? 1e-6f : 0.f);
      }
    __syncthreads();
    #pragma unroll
    for (int u=0;u<4;++u)
      #pragma unroll
      for (int v=0;v<4;++v) As[ty*4+u][tx*4+v] = kv[u][v];
    __syncthreads();
    factor64_reg(As, lkdiag, sdg, 0, t);
  } else {
    for (int idx=bid; idx<528; idx+=GRIDN-1){
      int r=0; while ((r+1)*(r+2)/2 <= idx) ++r;
      int c = idx - r*(r+1)/2;
      __syncthreads();
      for (int p=t; p<128; p+=256){ int i=p>>1, h=p&1;
        *(float4*)&As[i][h*4] = *(const float4*)&z[(size_t)(r*64+i)*DD + h*4];
        *(float4*)&Bs[i][h*4] = *(const float4*)&z[(size_t)(c*64+i)*DD + h*4]; }
      __syncthreads();
      #pragma unroll
      for (int u=0;u<4;++u){
        float4 o;
        float* ov = (float*)&o;
        #pragma unroll
        for (int v=0;v<4;++v){
          float d2=0.f;
          #pragma unroll
          for (int d=0;d<8;++d){ float df=As[ty*4+u][d]-Bs[tx*4+v][d]; d2+=df*df; }
          float val = __expf(-2.f*d2);
          if (r*64+ty*4+u == c*64+tx*4+v) val += 1e-6f;
          ov[v] = val;
        }
        *(float4*)&kuu[(size_t)(r*64+ty*4+u)*MM + c*64 + tx*4] = o;
      }
    }
  }
  gbar_h(bar, xcc, myN, nxcd, gen);

  // ---- phase 1: blocked Cholesky with diag lookahead ----
  for (int kb=0; kb<31; ++kb){
    int R = MM - (kb+1)*64;
    int nact = (R + 255) >> 8;
    if (bid < nact){
      for (int p=t; p<1024; p+=256)
        *(float4*)&As[p>>4][(p&15)*4] = *(const float4*)&lkdiag[kb*4096 + p*4];
      if (t < 64) sd[t] = sdg[kb*64 + t];
      __syncthreads();
      int row = (kb+1)*64 + bid*256 + t;
      if (row < MM){
        float xr[64];
        float* ap = kuu + (size_t)row*MM + kb*64;
        #pragma unroll
        for (int c4=0; c4<16; ++c4) *(float4*)&xr[c4*4] = *(const float4*)&ap[c4*4];
        #pragma unroll
        for (int j=0; j<64; ++j){
          float xj = xr[j]*sd[j];
          xr[j] = xj;
          #pragma unroll
          for (int c=j+1; c<64; ++c) xr[c] -= xj*As[c][j];
        }
        #pragma unroll
        for (int c4=0; c4<16; ++c4) *(float4*)&ap[c4*4] = *(float4*)&xr[c4*4];
      }
    }
    gbar_h(bar, xcc, myN, nxcd, gen);

    int T = NB-1 - kb;
    int ntiles = T*(T+1)/2;
    if (bid == 0){
      // tile (kb+1,kb+1): SYRK + immediate diag factorization (lookahead)
      int bi = kb+1;
      stage64(As, kuu + (size_t)(bi*64)*MM + kb*64, MM, t);
      __syncthreads();
      float acc[4][4] = {};
      tile_syrk_step(acc, As, As, tx, ty);
      __syncthreads();
      #pragma unroll
      for (int u=0;u<4;++u)
        #pragma unroll
        for (int v=0;v<4;++v) Bs[ty*4+u][tx*4+v] = acc[u][v];
      __syncthreads();
      for (int p=t;p<1024;p+=256){
        int i=p>>4, c4=p&15;
        float4 kv = *(const float4*)&kuu[(size_t)(bi*64+i)*MM + bi*64 + c4*4];
        float4 bv = *(float4*)&Bs[i][c4*4];
        float4 o; o.x=kv.x-bv.x; o.y=kv.y-bv.y; o.z=kv.z-bv.z; o.w=kv.w-bv.w;
        *(float4*)&As[i][c4*4] = o;
      }
      __syncthreads();
      factor64_reg(As, lkdiag, sdg, kb+1, t);
    } else {
      for (int idx=bid; idx<ntiles; idx+=GRIDN-1){
        int r=0; while ((r+1)*(r+2)/2 <= idx) ++r;
        int c = idx - r*(r+1)/2;
        int bi = kb+1+r, bc = kb+1+c;
        __syncthreads();
        stage64(As, kuu + (size_t)(bi*64)*MM + kb*64, MM, t);
        stage64(Bs, kuu + (size_t)(bc*64)*MM + kb*64, MM, t);
        __syncthreads();
        float acc[4][4] = {};
        tile_syrk_step(acc, As, Bs, tx, ty);
        #pragma unroll
        for (int u=0;u<4;++u){
          float4* dst = (float4*)&kuu[(size_t)(bi*64+ty*4+u)*MM + bc*64 + tx*4];
          float4 o = *dst;
          o.x-=acc[u][0]; o.y-=acc[u][1]; o.z-=acc[u][2]; o.w-=acc[u][3];
          *dst = o;
        }
      }
    }
    gbar_h(bar, xcc, myN, nxcd, gen);
  }

  // ---- phase 2: invert 64x64 diagonal blocks (from lkdiag) ----
  if (bid < NB){
    stage64(As, lkdiag + bid*4096, 64, t);
    __syncthreads();
    if (t < 64){
      for (int j=0;j<64;++j){
        float s = (j==t)?1.f:0.f;
        for (int k=t;k<j;++k) s -= As[j][k]*Bs[k][t];
        Bs[j][t] = (j>=t)? s/As[j][j] : 0.f;
      }
    }
    __syncthreads();
    for (int p=t;p<1024;p+=256){ int i=p>>4, c4=p&15;
      *(float4*)&linv[(size_t)(bid*64+i)*MM + bid*64 + c4*4] = *(float4*)&Bs[i][c4*4]; }
  }
  gbar_h(bar, xcc, myN, nxcd, gen);

  // ---- phase 3: recursive-doubling inversion: X21 = -X22 * A21 * X11 ----
  // level 0 fused (both GEMMs are task-local)
  for (int idx=bid; idx<16; idx+=GRIDN){
    int m = idx;
    __syncthreads();
    stage64(As, kuu  + (size_t)((2*m+1)*64)*MM + (2*m)*64, MM, t);
    stage64(Bs, linv + (size_t)((2*m)*64)*MM   + (2*m)*64, MM, t);
    __syncthreads();
    float acc[4][4]={};
    tile_gemm_step(acc, As, Bs, tx, ty);
    __syncthreads();
    #pragma unroll
    for (int u=0;u<4;++u)
      #pragma unroll
      for (int v=0;v<4;++v) Bs[ty*4+u][tx*4+v] = acc[u][v];
    stage64(As, linv + (size_t)((2*m+1)*64)*MM + (2*m+1)*64, MM, t);
    __syncthreads();
    float o[4][4]={};
    tile_gemm_step(o, As, Bs, tx, ty);
    #pragma unroll
    for (int u=0;u<4;++u)
      *(float4*)&linv[(size_t)((2*m+1)*64+ty*4+u)*MM + (2*m)*64 + tx*4] =
          make_float4(-o[u][0],-o[u][1],-o[u][2],-o[u][3]);
  }
  gbar_h(bar, xcc, myN, nxcd, gen);

  for (int s=1; s<5; ++s){
    int nb = 1<<s, mc = 16>>s, b = 64<<s;
    int tiles = mc*nb*nb;
    for (int idx=bid; idx<tiles; idx+=GRIDN){
      int m = idx/(nb*nb), r2 = idx%(nb*nb);
      int ti = r2/nb, tj = r2%nb;
      int rb = m*2*nb + nb + ti, cb0 = m*2*nb;
      float acc[4][4]={};
      for (int k=tj; k<nb; ++k){
        __syncthreads();
        stage64(As, kuu  + (size_t)(rb*64)*MM + (cb0+k)*64, MM, t);
        stage64(Bs, linv + (size_t)((cb0+k)*64)*MM + (cb0+tj)*64, MM, t);
        __syncthreads();
        tile_gemm_step(acc, As, Bs, tx, ty);
      }
      float* pm = ptmp + (size_t)m*b*b;
      #pragma unroll
      for (int u=0;u<4;++u)
        *(float4*)&pm[(size_t)(ti*64+ty*4+u)*b + tj*64 + tx*4] =
            make_float4(acc[u][0],acc[u][1],acc[u][2],acc[u][3]);
    }
    gbar_h(bar, xcc, myN, nxcd, gen);
    for (int idx=bid; idx<tiles; idx+=GRIDN){
      int m = idx/(nb*nb), r2 = idx%(nb*nb);
      int ti = r2/nb, tj = r2%nb;
      int rb = m*2*nb + nb + ti;
      const float* pm = ptmp + (size_t)m*b*b;
      float acc[4][4]={};
      for (int k=0; k<=ti; ++k){
        __syncthreads();
        stage64(As, linv + (size_t)(rb*64)*MM + (m*2*nb+nb+k)*64, MM, t);
        stage64(Bs, pm + (size_t)(k*64)*b + tj*64, b, t);
        __syncthreads();
        tile_gemm_step(acc, As, Bs, tx, ty);
      }
      #pragma unroll
      for (int u=0;u<4;++u)
        *(float4*)&linv[(size_t)(rb*64+ty*4+u)*MM + (m*2*nb+tj)*64 + tx*4] =
            make_float4(-acc[u][0],-acc[u][1],-acc[u][2],-acc[u][3]);
    }
    gbar_h(bar, xcc, myN, nxcd, gen);
  }

  // ---- phase 4: W = Linv @ tril(qL) (both GPs), then alpha = Linv @ qm ----
  for (int idx=bid; idx<2*528; idx+=GRIDN){
    int gp = idx/528, rem = idx%528;
    int bi=0; while ((bi+1)*(bi+2)/2 <= rem) ++bi;
    int bj = rem - bi*(bi+1)/2;
    const float* ql = gp ? qlg : qlf;
    float* w        = gp ? wg  : wf;
    float acc[4][4]={};
    for (int bk=bj; bk<=bi; ++bk){
      __syncthreads();
      stage64(As, linv + (size_t)(bi*64)*MM + bk*64, MM, t);
      stage64(Bs, ql   + (size_t)(bk*64)*MM + bj*64, MM, t);
      __syncthreads();
      if (bk==bj){
        for (int p=t;p<4096;p+=256){ int i=p>>6, c=p&63; if (i<c) Bs[i][c]=0.f; }
        __syncthreads();
      }
      tile_gemm_step(acc, As, Bs, tx, ty);
    }
    #pragma unroll
    for (int u=0;u<4;++u)
      *(float4*)&w[(size_t)(bi*64+ty*4+u)*MM + bj*64 + tx*4] =
          make_float4(acc[u][0],acc[u][1],acc[u][2],acc[u][3]);
  }
  {
    int gw = bid*4 + (t>>6), l = t&63;
    for (int job=gw; job<4096; job+=GRIDN*4){
      int gp = job>>11, r = job&2047;
      const float* qm = gp ? qmg : qmf;
      float s=0.f;
      for (int c=l; c<=r; c+=64) s += linv[(size_t)r*MM+c]*qm[c];
      #pragma unroll
      for (int off=32; off; off>>=1) s += __shfl_down(s, off, 64);
      if (l==0) (gp ? ag : af)[r] = s;
    }
  }
}

// ================= small kernels (pre/post) =================

__global__ __launch_bounds__(256) void zfrag_kernel(const float* __restrict__ z,
    short* __restrict__ zfh, short* __restrict__ zfl, float* __restrict__ zn2){
  int zr = blockIdx.x*256 + threadIdx.x;
  float v[DD]; float s = 0.f;
  #pragma unroll
  for (int d=0; d<DD; ++d){ v[d] = z[zr*DD + d]; s += v[d]*v[d]; }
  zn2[zr] = s;
  size_t base = (size_t)(zr >> 4)*512 + (zr & 15)*32;
  #pragma unroll
  for (int k=0; k<32; ++k){
    short h = 0, lo = 0;
    if (k < DD) bfsplit(v[k], h, lo);
    zfh[base + k] = h; zfl[base + k] = lo;
  }
}

__global__ __launch_bounds__(256) void red_small(const float* __restrict__ lkd,
    const float* __restrict__ qlf, const float* __restrict__ qlg,
    const float* __restrict__ af, const float* __restrict__ ag,
    float* __restrict__ scal){
  __shared__ float scratch[4];
  float ldk=0, ldf=0, ldg=0, a2f=0, a2g=0;
  for (int i=threadIdx.x;i<MM;i+=256){
    int kb = i>>6, r = i&63;
    ldk += __logf(lkd[kb*4096 + r*64 + r]);
    ldf += __logf(fabsf(qlf[(size_t)i*MM+i]));
    ldg += __logf(fabsf(qlg[(size_t)i*MM+i]));
    float v = af[i]; a2f += v*v;
    v = ag[i];       a2g += v*v;
  }
  float r;
  r = block_reduce(ldk, scratch); if (threadIdx.x==0) scal[0] = 2.f*r;
  r = block_reduce(ldf, scratch); if (threadIdx.x==0) scal[1] = 2.f*r;
  r = block_reduce(ldg, scratch); if (threadIdx.x==0) scal[2] = 2.f*r;
  r = block_reduce(a2f, scratch); if (threadIdx.x==0) scal[3] = r;
  r = block_reduce(a2g, scratch); if (threadIdx.x==0) scal[4] = r;
}

__global__ __launch_bounds__(256) void redw_kernel(const float* __restrict__ wf,
    const float* __restrict__ wg, float* __restrict__ scal){
  __shared__ float scratch[4];
  size_t start  = (size_t)blockIdx.x*256 + threadIdx.x;
  size_t stride = (size_t)gridDim.x*256;
  float sf=0, sg=0;
  for (size_t p=start;p<(size_t)MM*MM;p+=stride){
    float v=wf[p]; sf += v*v;
    v=wg[p];       sg += v*v;
  }
  float r = block_reduce(sf, scratch);
  if (threadIdx.x==0) atomicAdd(&scal[5], r);
  r = block_reduce(sg, scratch);
  if (threadIdx.x==0) atomicAdd(&scal[6], r);
}

__global__ void kl_kernel(const float* __restrict__ scal, float* __restrict__ out){
  float klf = 0.5f*(scal[5] + scal[3] - (float)MM + scal[0] - scal[1]);
  float klg = 0.5f*(scal[6] + scal[4] - (float)MM + scal[0] - scal[2]);
  out[0] += klf + klg;
}

__global__ __launch_bounds__(256) void split_rowmajor(const float* __restrict__ src,
    short* __restrict__ dh, short* __restrict__ dl){
  int p = blockIdx.x*256 + threadIdx.x;
  int chunk = p >> 9, wi = p & 511;
  int mo = chunk >> 6, ko = chunk & 63;
  int row = mo*16 + (wi >> 5), col = ko*32 + (wi & 31);
  float v = src[(size_t)row*MM + col];
  short h, lo; bfsplit(v, h, lo);
  dh[p] = h; dl[p] = lo;
}

__global__ __launch_bounds__(256) void split_transpose(const float* __restrict__ src,
    short* __restrict__ dh, short* __restrict__ dl){
  __shared__ float tile[32][33];
  int t = threadIdx.x;
  int mb = blockIdx.x, kb = blockIdx.y;
  #pragma unroll
  for (int k=0;k<4;++k){
    int idx = t + k*256;
    int lr = idx >> 5, lc = idx & 31;
    tile[lr][lc] = src[(size_t)(kb*32+lr)*MM + mb*32 + lc];
  }
  __syncthreads();
  #pragma unroll
  for (int e=0;e<4;++e){
    int p = t*4 + e;
    int c = p >> 9, wi = p & 511;
    int i = (wi >> 5) & 15, kk = wi & 31;
    float v = tile[kk][c*16 + i];
    short h, lo; bfsplit(v, h, lo);
    size_t gp = ((size_t)(mb*2 + c)*64 + kb)*512 + wi;
    dh[gp] = h; dl[gp] = lo;
  }
}

__global__ __launch_bounds__(256, 2) void tt_mfma(
    const float* __restrict__ x, const float* __restrict__ zn2,
    const short* __restrict__ zfh, const short* __restrict__ zfl,
    const short* __restrict__ lvh, const short* __restrict__ lvl,
    short* __restrict__ tth, short* __restrict__ ttl){
  __shared__ __align__(16) short lAh[8192], lAl[8192], lBh[8192], lBl[8192];
  int t = threadIdx.x;
  int l = t & 63, w = t >> 6;
  int istrip = blockIdx.x, bj2 = blockIdx.y;
  int li = l & 15, q = l >> 4;
  int lofs = li*32 + q*8;
  int wn4 = (w>>1)*4, wm4 = (w&1)*4;

  short8 xh[2], xl[2];
  float xn2v[8];
  {
    float xn2t[2];
    #pragma unroll
    for (int tn=0; tn<2; ++tn){
      int n = istrip*128 + w*32 + tn*16 + li;
      const float4* xp = (const float4*)(x + (size_t)n*DD);
      float4 p0 = xp[0], p1 = xp[1];
      float v[8] = {p0.x,p0.y,p0.z,p0.w,p1.x,p1.y,p1.z,p1.w};
      float s = 0.f;
      #pragma unroll
      for (int d=0; d<8; ++d) s += v[d]*v[d];
      xn2t[tn] = s;
      short8 hh, ll;
      #pragma unroll
      for (int j=0; j<8; ++j){
        short h=0, lo=0;
        if (q==0) bfsplit(v[j], h, lo);
        hh[j]=h; ll[j]=lo;
      }
      xh[tn]=hh; xl[tn]=ll;
    }
    #pragma unroll
    for (int tn=0; tn<2; ++tn)
      #pragma unroll
      for (int r=0; r<4; ++r)
        xn2v[tn*4+r] = __shfl(xn2t[tn], q*4 + r, 64);
  }

  float4v acc[4][4];
  #pragma unroll
  for (int i=0;i<4;++i)
    #pragma unroll
    for (int j=0;j<4;++j) acc[i][j] = f4zero();

  int nkt = 2*bj2 + 2;
  for (int bk=0; bk<nkt; ++bk){
    __syncthreads();
    {
      short8 zh[4], zl[4];
      float zt2[4];
      #pragma unroll
      for (int tz=0; tz<4; ++tz){
        size_t zo = (size_t)(bk*4 + tz)*512 + lofs;
        zh[tz] = *(const short8*)(zfh + zo);
        zl[tz] = *(const short8*)(zfl + zo);
        zt2[tz] = zn2[bk*64 + tz*16 + li];
      }
      #pragma unroll
      for (int tn=0; tn<2; ++tn){
        #pragma unroll
        for (int tz=0; tz<4; ++tz){
          float4v s4 = mfma3(xh[tn], xl[tn], zh[tz], zl[tz], f4zero());
          #pragma unroll
          for (int r=0; r<4; ++r){
            float e = __expf(4.f*s4[r] - 2.f*(xn2v[tn*4+r] + zt2[tz]));
            short h, lo; bfsplit(e, h, lo);
            int pos = ((w*2+tn)*2 + (tz>>1))*512 + (q*4+r)*32 + (tz&1)*16 + li;
            lAh[pos] = h; lAl[pos] = lo;
          }
        }
      }
    }
    #pragma unroll
    for (int c4 = t; c4 < 1024; c4 += 256){
      int ch = c4 >> 6, wdi = c4 & 63;
      size_t g = ((size_t)(bj2*8 + (ch>>1))*64 + (size_t)(bk*2 + (ch&1)))*64 + wdi;
      ((uint4*)lBh)[c4] = ((const uint4*)lvh)[g];
      ((uint4*)lBl)[c4] = ((const uint4*)lvl)[g];
    }
    __syncthreads();
    #pragma unroll
    for (int s=0; s<2; ++s){
      short8 ah[4], al[4], bh[4], bl[4];
      #pragma unroll
      for (int tn=0; tn<4; ++tn){
        int off = ((wn4+tn)*2 + s)*512 + lofs;
        ah[tn] = *(const short8*)&lAh[off];
        al[tn] = *(const short8*)&lAl[off];
      }
      #pragma unroll
      for (int tm=0; tm<4; ++tm){
        int off = ((wm4+tm)*2 + s)*512 + lofs;
        bh[tm] = *(const short8*)&lBh[off];
        bl[tm] = *(const short8*)&lBl[off];
      }
      #pragma unroll
      for (int tn=0; tn<4; ++tn)
        #pragma unroll
        for (int tm=0; tm<4; ++tm)
          acc[tn][tm] = mfma3(ah[tn], al[tn], bh[tm], bl[tm], acc[tn][tm]);
    }
  }
  #pragma unroll
  for (int tn=0; tn<4; ++tn){
    int no_g = istrip*8 + wn4 + tn;
    #pragma unroll
    for (int tm=0; tm<4; ++tm){
      int mo_g = bj2*4 + (w&1)*2 + (tm>>1);
      size_t cb = ((size_t)no_g*64 + mo_g)*512;
      #pragma unroll
      for (int r=0; r<4; ++r){
        short h, lo; bfsplit(acc[tn][tm][r], h, lo);
        size_t pos = cb + (q*4+r)*32 + (tm&1)*16 + li;
        tth[pos] = h; ttl[pos] = lo;
      }
    }
  }
}

__global__ __launch_bounds__(256) void lin_v2(const short* __restrict__ tth,
    const short* __restrict__ ttl, const float* __restrict__ af, const float* __restrict__ ag,
    float* __restrict__ t2, float* __restrict__ lf, float* __restrict__ lg){
  int t = threadIdx.x;
  int w = t >> 6, l = t & 63;
  int n = blockIdx.x*4 + w;
  int g = l >> 2, j = l & 3;
  float s2=0.f, sf=0.f, sg=0.f;
  #pragma unroll
  for (int it=0; it<4; ++it){
    int ck = g + it*16;
    size_t off = ((size_t)(n>>4)*64 + ck)*512 + (n&15)*32 + j*8;
    short8 h8 = *(const short8*)(tth + off);
    short8 l8 = *(const short8*)(ttl + off);
    int m0 = ck*32 + j*8;
    float4 a0 = *(const float4*)(af + m0), a1 = *(const float4*)(af + m0 + 4);
    float4 g0 = *(const float4*)(ag + m0), g1 = *(const float4*)(ag + m0 + 4);
    float av[8] = {a0.x,a0.y,a0.z,a0.w,a1.x,a1.y,a1.z,a1.w};
    float gv[8] = {g0.x,g0.y,g0.z,g0.w,g1.x,g1.y,g1.z,g1.w};
    #pragma unroll
    for (int e=0; e<8; ++e){
      float tv = bf2f(h8[e]) + bf2f(l8[e]);
      s2 += tv*tv; sf += tv*av[e]; sg += tv*gv[e];
    }
  }
  #pragma unroll
  for (int off=32; off; off>>=1){
    s2 += __shfl_down(s2, off, 64);
    sf += __shfl_down(sf, off, 64);
    sg += __shfl_down(sg, off, 64);
  }
  if (l==0){ t2[n] = s2; lf[n] = sf; lg[n] = sg; }
}

__global__ __launch_bounds__(256, 2) void quad_mfma(
    const short* __restrict__ tth, const short* __restrict__ ttl,
    const short* __restrict__ wfh, const short* __restrict__ wfl,
    const short* __restrict__ wgh, const short* __restrict__ wgl,
    float* __restrict__ vfq, float* __restrict__ vgq){
  __shared__ __align__(16) short lAh[8192], lAl[8192], lBh[8192], lBl[8192];
  int t = threadIdx.x, l = t & 63, w = t >> 6;
  int istrip = blockIdx.x, bj2 = blockIdx.y;
  const short* gbh = blockIdx.z ? wgh : wfh;
  const short* gbl = blockIdx.z ? wgl : wfl;
  float* vq = blockIdx.z ? vgq : vfq;
  int li = l & 15, q = l >> 4;
  int lofs = li*32 + q*8;
  int wn4 = (w>>1)*4, wm4 = (w&1)*4;

  float4v acc[4][4];
  #pragma unroll
  for (int i=0;i<4;++i)
    #pragma unroll
    for (int j=0;j<4;++j) acc[i][j] = f4zero();

  for (int bk=2*bj2; bk<32; ++bk){
    __syncthreads();
    #pragma unroll
    for (int c4 = t; c4 < 1024; c4 += 256){
      int ch = c4 >> 6, wdi = c4 & 63;
      size_t ga = ((size_t)(istrip*8 + (ch>>1))*64 + (size_t)(bk*2 + (ch&1)))*64 + wdi;
      ((uint4*)lAh)[c4] = ((const uint4*)tth)[ga];
      ((uint4*)lAl)[c4] = ((const uint4*)ttl)[ga];
      size_t gb = ((size_t)(bj2*8 + (ch>>1))*64 + (size_t)(bk*2 + (ch&1)))*64 + wdi;
      ((uint4*)lBh)[c4] = ((const uint4*)gbh)[gb];
      ((uint4*)lBl)[c4] = ((const uint4*)gbl)[gb];
    }
    __syncthreads();
    #pragma unroll
    for (int s=0; s<2; ++s){
      short8 ah[4], al[4], bh[4], bl[4];
      #pragma unroll
      for (int tn=0; tn<4; ++tn){
        int off = ((wn4+tn)*2 + s)*512 + lofs;
        ah[tn] = *(const short8*)&lAh[off];
        al[tn] = *(const short8*)&lAl[off];
      }
      #pragma unroll
      for (int tm=0; tm<4; ++tm){
        int off = ((wm4+tm)*2 + s)*512 + lofs;
        bh[tm] = *(const short8*)&lBh[off];
        bl[tm] = *(const short8*)&lBl[off];
      }
      #pragma unroll
      for (int tn=0; tn<4; ++tn)
        #pragma unroll
        for (int tm=0; tm<4; ++tm)
          acc[tn][tm] = mfma3(ah[tn], al[tn], bh[tm], bl[tm], acc[tn][tm]);
    }
  }
  float rs[16];
  #pragma unroll
  for (int tn=0; tn<4; ++tn)
    #pragma unroll
    for (int r=0; r<4; ++r){
      float s = 0.f;
      #pragma unroll
      for (int tm=0; tm<4; ++tm){ float v = acc[tn][tm][r]; s += v*v; }
      rs[tn*4+r] = s;
    }
  #pragma unroll
  for (int off=8; off; off>>=1)
    #pragma unroll
    for (int k=0; k<16; ++k) rs[k] += __shfl_down(rs[k], off, 16);
  if (li == 0){
    #pragma unroll
    for (int tn=0; tn<4; ++tn)
      #pragma unroll
      for (int r=0; r<4; ++r){
        int n = istrip*128 + (w>>1)*64 + tn*16 + q*4 + r;
        atomicAdd(&vq[n], rs[tn*4+r]);
      }
  }
}

__global__ __launch_bounds__(256) void final_kernel(const float* __restrict__ y,
    const float* __restrict__ t2, const float* __restrict__ lf, const float* __restrict__ lg,
    const float* __restrict__ vfq, const float* __restrict__ vgq, float* __restrict__ out){
  __shared__ float scratch[4];
  int i = blockIdx.x*256 + threadIdx.x;
  float mf = lf[i], mg = lg[i];
  float vf = 1.f + vfq[i] - t2[i];
  float vg = 1.f + vgq[i] - t2[i];
  float dy = y[i] - mf;
  float e = -HLOG2PI - 0.5f*mg - 0.5f*(dy*dy + vf)*__expf(-mg + 0.5f*vg);
  float r = block_reduce(e, scratch);
  if (threadIdx.x==0) atomicAdd(out, -r);
}

extern "C" void kernel_launch(void* const* d_in, const int* in_sizes, int n_in,
                              void* d_out, int out_size, void* d_ws, size_t ws_size,
                              hipStream_t stream){
  (void)in_sizes; (void)n_in; (void)out_size; (void)ws_size;
  const float* x   = (const float*)d_in[0];
  const float* y   = (const float*)d_in[1];
  const float* z   = (const float*)d_in[2];
  const float* qmf = (const float*)d_in[3];
  const float* qlf = (const float*)d_in[4];
  const float* qmg = (const float*)d_in[5];
  const float* qlg = (const float*)d_in[6];
  float* out = (float*)d_out;
  char* Bw = (char*)d_ws;

  float* kuu  = (float*)Bw;
  float* linv = (float*)(Bw + SZB);
  float* wf   = (float*)(Bw + 2*SZB);
  float* wg   = (float*)(Bw + 3*SZB);
  short* lvh  = (short*)Bw;
  short* lvl  = (short*)(Bw + SZB/2);
  short* wfh  = (short*)(Bw + SZB);
  short* wfl  = (short*)(Bw + SZB + SZB/2);
  short* wgh  = (short*)(Bw + 2*SZB);
  short* wgl  = (short*)(Bw + 2*SZB + SZB/2);
  short* tth  = (short*)(Bw + 3*SZB);
  short* ttl  = (short*)(Bw + 3*SZB + (size_t)NN*MM*2);
  float* ptmp   = (float*)(Bw + 4*SZB);                    // 4 MB (dead tt region)
  float* lkdiag = (float*)(Bw + 4*SZB + (size_t)4194304);  // 512 KB
  float* sdg    = (float*)(Bw + 4*SZB + (size_t)4194304 + (size_t)524288); // 8 KB
  float* sm   = (float*)(Bw + 3*SZB + (size_t)NN*MM*4);
  float* af = sm;          float* ag = af + MM;
  float* t2 = ag + MM;     float* lf = t2 + NN;   float* lg = lf + NN;
  float* vfq = lg + NN;    float* vgq = vfq + NN; float* scal = vgq + NN;
  int*   bar = (int*)(scal + 64);    // 2048 ints (8 KB) of barrier state
  float* zn2 = scal + 64 + 2048;
  short* zfh = (short*)(zn2 + MM);
  short* zfl = zfh + MM*32;

  hipMemsetAsync(out, 0, sizeof(float), stream);
  hipMemsetAsync(vfq, 0, (size_t)(2*NN + 64 + 2048)*sizeof(float), stream); // vfq,vgq,scal,bar
  hipMemsetAsync(wf,  0, 2*SZB, stream);    // W upper triangles must be 0
  hipMemsetAsync(linv,0, SZB,   stream);    // Linv upper must be 0

  zfrag_kernel<<<MM/256, 256, 0, stream>>>(z, zfh, zfl, zn2);

  factor_coop<<<GRIDN, 256, 0, stream>>>(z, qlf, qlg, qmf, qmg,
                                         kuu, linv, wf, wg, af, ag,
                                         ptmp, lkdiag, sdg, bar);

  red_small<<<1, 256, 0, stream>>>(lkdiag, qlf, qlg, af, ag, scal);
  redw_kernel<<<512, 256, 0, stream>>>(wf, wg, scal);
  kl_kernel<<<1, 1, 0, stream>>>(scal, out);

  split_rowmajor<<<MM*MM/256, 256, 0, stream>>>(linv, lvh, lvl);
  split_transpose<<<dim3(MM/32, MM/32), 256, 0, stream>>>(wf, wfh, wfl);
  split_transpose<<<dim3(MM/32, MM/32), 256, 0, stream>>>(wg, wgh, wgl);

  tt_mfma<<<dim3(NN/128, MM/128), 256, 0, stream>>>(x, zn2, zfh, zfl, lvh, lvl, tth, ttl);
  lin_v2<<<NN/4, 256, 0, stream>>>(tth, ttl, af, ag, t2, lf, lg);
  quad_mfma<<<dim3(NN/128, MM/128, 2), 256, 0, stream>>>(tth, ttl, wfh, wfl, wgh, wgl, vfq, vgq);
  final_kernel<<<NN/256, 256, 0, stream>>>(y, t2, lf, lg, vfq, vgq, out);
}

// Round 8
// 4273.664 us; speedup vs baseline: 1.1401x; 1.1401x over previous
//
#include <hip/hip_runtime.h>
#include <math.h>

// ChainedGP v8: v7 with barrier COUNT cut 74 -> 42 (the ~43us/barrier cost is
// the L2 tag-walk of wbl2/inv fences — invariant to who issues them, so fuse
// phases instead): (1) TRSM folded into the SYRK phase (redundant per-tile
// in-LDS TRSM; TRSM'd column published to separate ltri buffer — kuu never
// overwritten mid-phase), one barrier per panel; (2) phase-3 level-1 fused
// per-m. Diag lookahead now inside the fused phase (block 0, tile idx 0).
#define NN 16384
#define MM 2048
#define DD 8
#define NB 32                     // MM/64
#define GRIDN 256                 // factor kernel grid (co-resident, 1/CU)
#define SZB ((size_t)16777216)    // 2048*2048*4 bytes

constexpr float HLOG2PI = 0.91893853320467274178f;

using short8  = __attribute__((ext_vector_type(8))) short;
using float4v = __attribute__((ext_vector_type(4))) float;

__device__ __forceinline__ float4v f4zero(){ float4v v; v[0]=0.f; v[1]=0.f; v[2]=0.f; v[3]=0.f; return v; }

__device__ __forceinline__ void bfsplit(float v, short& h, short& lo){
  unsigned b = __float_as_uint(v);
  h = (short)(b >> 16);
  float hf = __uint_as_float(b & 0xFFFF0000u);
  lo = (short)(__float_as_uint(v - hf) >> 16);
}
__device__ __forceinline__ float bf2f(short s){
  return __uint_as_float(((unsigned)(unsigned short)s) << 16);
}
__device__ __forceinline__ float4v mfma3(short8 ah, short8 al, short8 bh, short8 bl, float4v c){
  c = __builtin_amdgcn_mfma_f32_16x16x32_bf16(ah, bh, c, 0, 0, 0);
  c = __builtin_amdgcn_mfma_f32_16x16x32_bf16(ah, bl, c, 0, 0, 0);
  c = __builtin_amdgcn_mfma_f32_16x16x32_bf16(al, bh, c, 0, 0, 0);
  return c;
}

// bootstrap barrier (used once, for census)
__device__ __forceinline__ void gbar0(int* cnt, int* flag, int& gen){
  __syncthreads();
  if (threadIdx.x == 0){
    ++gen;
    __builtin_amdgcn_fence(__ATOMIC_RELEASE, "agent");
    int old = __hip_atomic_fetch_add(cnt, 1, __ATOMIC_RELAXED, __HIP_MEMORY_SCOPE_AGENT);
    if (old == gen*GRIDN - 1){
      __builtin_amdgcn_fence(__ATOMIC_ACQ_REL, "agent");
      __hip_atomic_store(flag, gen, __ATOMIC_RELAXED, __HIP_MEMORY_SCOPE_AGENT);
    } else {
      while (__hip_atomic_load(flag, __ATOMIC_RELAXED, __HIP_MEMORY_SCOPE_AGENT) < gen)
        __builtin_amdgcn_s_sleep(8);
    }
    __builtin_amdgcn_fence(__ATOMIC_ACQUIRE, "agent");
  }
  __syncthreads();
}

// hierarchical XCD-aware barrier (one release fence per XCD, per-block acquire)
__device__ __forceinline__ void gbar_h(int* bar, int xcc, int myN, int nxcd, int& gen){
  __syncthreads();
  if (threadIdx.x == 0){
    ++gen;
    int* lcnt  = bar + xcc*32;
    int* lflag = bar + 512 + xcc*32;
    int* gcnt  = bar + 1024;
    int* gflag = bar + 1056;
    int old = __hip_atomic_fetch_add(lcnt, 1, __ATOMIC_RELAXED, __HIP_MEMORY_SCOPE_AGENT);
    if (old == gen*myN - 1){
      __builtin_amdgcn_fence(__ATOMIC_RELEASE, "agent");
      int g = __hip_atomic_fetch_add(gcnt, 1, __ATOMIC_RELAXED, __HIP_MEMORY_SCOPE_AGENT);
      if (g == gen*nxcd - 1){
        __hip_atomic_store(gflag, gen, __ATOMIC_RELAXED, __HIP_MEMORY_SCOPE_AGENT);
      } else {
        while (__hip_atomic_load(gflag, __ATOMIC_RELAXED, __HIP_MEMORY_SCOPE_AGENT) < gen)
          __builtin_amdgcn_s_sleep(8);
      }
      __builtin_amdgcn_fence(__ATOMIC_ACQUIRE, "agent");
      __hip_atomic_store(lflag, gen, __ATOMIC_RELAXED, __HIP_MEMORY_SCOPE_AGENT);
    } else {
      while (__hip_atomic_load(lflag, __ATOMIC_RELAXED, __HIP_MEMORY_SCOPE_AGENT) < gen)
        __builtin_amdgcn_s_sleep(8);
      __builtin_amdgcn_fence(__ATOMIC_ACQUIRE, "agent");
    }
  }
  __syncthreads();
}

__device__ __forceinline__ float block_reduce(float v, float* scratch){
  int lane = threadIdx.x & 63;
  int w    = threadIdx.x >> 6;
  #pragma unroll
  for (int off=32; off; off>>=1) v += __shfl_down(v, off, 64);
  __syncthreads();
  if (lane==0) scratch[w] = v;
  __syncthreads();
  float r = 0.f;
  if (threadIdx.x < 4) r = scratch[threadIdx.x];
  if (w==0){ r += __shfl_down(r, 2, 64); r += __shfl_down(r, 1, 64); }
  return r;
}

// ---- 64x64 tile helpers (LDS row stride 68 floats) ----
__device__ __forceinline__ void stage64(float (*S)[68], const float* __restrict__ g, int ld, int t){
  #pragma unroll
  for (int p=t; p<1024; p+=256)
    *(float4*)&S[p>>4][(p&15)*4] = *(const float4*)&g[(size_t)(p>>4)*ld + (p&15)*4];
}
__device__ __forceinline__ void tile_gemm_step(float acc[4][4], const float (*As)[68], const float (*Bs)[68], int tx, int ty){
  for (int k=0;k<64;++k){
    float ar[4], bc4[4];
    #pragma unroll
    for (int u=0;u<4;++u){ ar[u]=As[ty*4+u][k]; bc4[u]=Bs[k][tx*4+u]; }
    #pragma unroll
    for (int u=0;u<4;++u)
      #pragma unroll
      for (int v=0;v<4;++v) acc[u][v] += ar[u]*bc4[v];
  }
}
__device__ __forceinline__ void tile_syrk_step(float acc[4][4], const float (*P)[68], const float (*Q)[68], int tx, int ty){
  for (int k=0;k<64;++k){
    float pr[4], qc[4];
    #pragma unroll
    for (int u=0;u<4;++u){ pr[u]=P[ty*4+u][k]; qc[u]=Q[tx*4+u][k]; }
    #pragma unroll
    for (int u=0;u<4;++u)
      #pragma unroll
      for (int v=0;v<4;++v) acc[u][v] += pr[u]*qc[v];
  }
}

// wave-0 register Cholesky of a 64x64 tile staged in S (LDS); no __syncthreads.
__device__ __forceinline__ void factor64_reg(const float (*S)[68],
    float* __restrict__ lkd, float* __restrict__ sdg_, int d, int t){
  if (t < 64){
    float xr[64];
    #pragma unroll
    for (int c4=0;c4<16;++c4) *(float4*)&xr[c4*4] = *(const float4*)&S[t][c4*4];
    float myrp = 1.f;
    #pragma unroll
    for (int j=0;j<64;++j){
      float ajj = __shfl(xr[j], j, 64);
      float piv = sqrtf(fmaxf(ajj, 1e-20f));
      float rp  = 1.f/piv;
      float val = xr[j]*rp;
      if (t==j){ xr[j] = piv; myrp = rp; }
      else if (t>j) xr[j] = val;
      else val = 0.f;
      #pragma unroll
      for (int c=j+1;c<64;++c){
        float vc = __shfl(val, c, 64);
        if (c<=t) xr[c] -= val*vc;
      }
    }
    #pragma unroll
    for (int c=0;c<64;++c) if (c>t) xr[c] = 0.f;
    #pragma unroll
    for (int c4=0;c4<16;++c4)
      *(float4*)&lkd[d*4096 + t*64 + c4*4] = *(float4*)&xr[c4*4];
    sdg_[d*64 + t] = myrp;
  }
}

// ================= fused factorization kernel (plain launch) =================
__global__ __launch_bounds__(256) void factor_coop(
    const float* __restrict__ z,
    const float* __restrict__ qlf, const float* __restrict__ qlg,
    const float* __restrict__ qmf, const float* __restrict__ qmg,
    float* __restrict__ kuu, float* __restrict__ linv,
    float* __restrict__ wf, float* __restrict__ wg,
    float* __restrict__ af, float* __restrict__ ag,
    float* __restrict__ ptmp, float* __restrict__ lkdiag,
    float* __restrict__ sdg, float* __restrict__ ltri, int* __restrict__ bar)
{
  __shared__ float As[64][68];
  __shared__ float Bs[64][68];
  __shared__ float Cs[64][68];
  __shared__ float sd[64];
  __shared__ int binfo[2];
  const int bid = blockIdx.x, t = threadIdx.x;
  const int tx = t & 15, ty = t >> 4;

  // ---- census: group blocks by physical XCD ----
  int xcc_r;
  asm volatile("s_getreg_b32 %0, hwreg(HW_REG_XCC_ID)" : "=s"(xcc_r));
  const int xcc = xcc_r & 15;
  if (t == 0)
    __hip_atomic_fetch_add(bar + 1152 + xcc*32, 1, __ATOMIC_RELAXED, __HIP_MEMORY_SCOPE_AGENT);
  int gen0 = 0;
  gbar0(bar + 1088, bar + 1120, gen0);
  if (t == 0){
    int myN = __hip_atomic_load(bar + 1152 + xcc*32, __ATOMIC_RELAXED, __HIP_MEMORY_SCOPE_AGENT);
    int nx = 0;
    for (int i=0;i<16;++i)
      nx += (__hip_atomic_load(bar + 1152 + i*32, __ATOMIC_RELAXED, __HIP_MEMORY_SCOPE_AGENT) > 0);
    binfo[0] = myN; binfo[1] = nx;
  }
  __syncthreads();
  const int myN = binfo[0], nxcd = binfo[1];
  int gen = 0;

  // ---- phase 0: Kuu lower tiles; block 0 computes+factors diag(0) ----
  if (bid == 0){
    for (int p=t; p<128; p+=256){ int i=p>>1, h=p&1;
      *(float4*)&As[i][h*4] = *(const float4*)&z[(size_t)i*DD + h*4]; }
    __syncthreads();
    float kv[4][4];
    #pragma unroll
    for (int u=0;u<4;++u)
      #pragma unroll
      for (int v=0;v<4;++v){
        float d2=0.f;
        #pragma unroll
        for (int d=0;d<8;++d){ float df=As[ty*4+u][d]-As[tx*4+v][d]; d2+=df*df; }
        kv[u][v] = __expf(-2.f*d2) + ((ty*4+u)==(tx*4+v) ? 1e-6f : 0.f);
      }
    __syncthreads();
    #pragma unroll
    for (int u=0;u<4;++u)
      #pragma unroll
      for (int v=0;v<4;++v) As[ty*4+u][tx*4+v] = kv[u][v];
    __syncthreads();
    factor64_reg(As, lkdiag, sdg, 0, t);
  } else {
    for (int idx=bid; idx<528; idx+=GRIDN-1){
      int r=0; while ((r+1)*(r+2)/2 <= idx) ++r;
      int c = idx - r*(r+1)/2;
      __syncthreads();
      for (int p=t; p<128; p+=256){ int i=p>>1, h=p&1;
        *(float4*)&As[i][h*4] = *(const float4*)&z[(size_t)(r*64+i)*DD + h*4];
        *(float4*)&Bs[i][h*4] = *(const float4*)&z[(size_t)(c*64+i)*DD + h*4]; }
      __syncthreads();
      #pragma unroll
      for (int u=0;u<4;++u){
        float4 o;
        float* ov = (float*)&o;
        #pragma unroll
        for (int v=0;v<4;++v){
          float d2=0.f;
          #pragma unroll
          for (int d=0;d<8;++d){ float df=As[ty*4+u][d]-Bs[tx*4+v][d]; d2+=df*df; }
          float val = __expf(-2.f*d2);
          if (r*64+ty*4+u == c*64+tx*4+v) val += 1e-6f;
          ov[v] = val;
        }
        *(float4*)&kuu[(size_t)(r*64+ty*4+u)*MM + c*64 + tx*4] = o;
      }
    }
  }
  gbar_h(bar, xcc, myN, nxcd, gen);

  // ---- phase 1: fused TRSM+SYRK, ONE barrier per panel ----
  // Tile (bi,bc), kb+1<=bc<=bi: stage pre-TRSM segments kuu(bi,kb),kuu(bc,kb),
  // TRSM them in-LDS with lkdiag[kb]; bc==kb+1 tiles publish ltri(bi,kb);
  // SYRK-update kuu(bi,bc). Tile (kb+1,kb+1) (block 0) instead subtracts in
  // LDS and factors -> lkdiag[kb+1] (lookahead).
  for (int kb=0; kb<31; ++kb){
    int T = NB-1 - kb;
    int ntiles = T*(T+1)/2;
    if (bid < ntiles){
      stage64(Cs, lkdiag + kb*4096, 64, t);
      if (t < 64) sd[t] = sdg[kb*64 + t];
    }
    for (int idx=bid; idx<ntiles; idx+=GRIDN){
      int r=0; while ((r+1)*(r+2)/2 <= idx) ++r;
      int c = idx - r*(r+1)/2;
      int bi = kb+1+r, bc = kb+1+c;
      __syncthreads();
      stage64(As, kuu + (size_t)(bi*64)*MM + kb*64, MM, t);
      if (bc != bi) stage64(Bs, kuu + (size_t)(bc*64)*MM + kb*64, MM, t);
      __syncthreads();
      {
        int w = t>>6, l = t&63;
        if (w==0 || (w==1 && bc!=bi)){
          float (*S)[68] = (w==0)? As : Bs;
          float xr[64];
          #pragma unroll
          for (int c4=0;c4<16;++c4) *(float4*)&xr[c4*4] = *(const float4*)&S[l][c4*4];
          #pragma unroll
          for (int j=0;j<64;++j){
            float xj = xr[j]*sd[j];
            xr[j] = xj;
            #pragma unroll
            for (int cc=j+1;cc<64;++cc) xr[cc] -= xj*Cs[cc][j];
          }
          #pragma unroll
          for (int c4=0;c4<16;++c4) *(float4*)&S[l][c4*4] = *(float4*)&xr[c4*4];
        }
      }
      __syncthreads();
      if (bc == kb+1){
        for (int p=t;p<1024;p+=256)
          *(float4*)&ltri[(size_t)(bi*64+(p>>4))*MM + kb*64 + (p&15)*4] =
              *(float4*)&As[p>>4][(p&15)*4];
      }
      float acc[4][4] = {};
      tile_syrk_step(acc, As, (bc==bi)? As : Bs, tx, ty);
      if (bi==kb+1 && bc==kb+1){
        __syncthreads();
        #pragma unroll
        for (int u=0;u<4;++u)
          #pragma unroll
          for (int v=0;v<4;++v) Bs[ty*4+u][tx*4+v] = acc[u][v];
        __syncthreads();
        for (int p=t;p<1024;p+=256){
          int i=p>>4, c4=p&15;
          float4 kv = *(const float4*)&kuu[(size_t)(bi*64+i)*MM + bi*64 + c4*4];
          float4 bv = *(float4*)&Bs[i][c4*4];
          float4 o; o.x=kv.x-bv.x; o.y=kv.y-bv.y; o.z=kv.z-bv.z; o.w=kv.w-bv.w;
          *(float4*)&As[i][c4*4] = o;
        }
        __syncthreads();
        factor64_reg(As, lkdiag, sdg, kb+1, t);
      } else {
        #pragma unroll
        for (int u=0;u<4;++u){
          float4* dst = (float4*)&kuu[(size_t)(bi*64+ty*4+u)*MM + bc*64 + tx*4];
          float4 o = *dst;
          o.x-=acc[u][0]; o.y-=acc[u][1]; o.z-=acc[u][2]; o.w-=acc[u][3];
          *dst = o;
        }
      }
    }
    gbar_h(bar, xcc, myN, nxcd, gen);
  }

  // ---- phase 2: invert 64x64 diagonal blocks (from lkdiag) ----
  if (bid < NB){
    stage64(As, lkdiag + bid*4096, 64, t);
    __syncthreads();
    if (t < 64){
      for (int j=0;j<64;++j){
        float s = (j==t)?1.f:0.f;
        for (int k=t;k<j;++k) s -= As[j][k]*Bs[k][t];
        Bs[j][t] = (j>=t)? s/As[j][j] : 0.f;
      }
    }
    __syncthreads();
    for (int p=t;p<1024;p+=256){ int i=p>>4, c4=p&15;
      *(float4*)&linv[(size_t)(bid*64+i)*MM + bid*64 + c4*4] = *(float4*)&Bs[i][c4*4]; }
  }
  gbar_h(bar, xcc, myN, nxcd, gen);

  // ---- phase 3: recursive-doubling inversion (A21 read from ltri) ----
  // level 0 fused (task-local)
  for (int idx=bid; idx<16; idx+=GRIDN){
    int m = idx;
    __syncthreads();
    stage64(As, ltri + (size_t)((2*m+1)*64)*MM + (2*m)*64, MM, t);
    stage64(Bs, linv + (size_t)((2*m)*64)*MM   + (2*m)*64, MM, t);
    __syncthreads();
    float acc[4][4]={};
    tile_gemm_step(acc, As, Bs, tx, ty);
    __syncthreads();
    #pragma unroll
    for (int u=0;u<4;++u)
      #pragma unroll
      for (int v=0;v<4;++v) Bs[ty*4+u][tx*4+v] = acc[u][v];
    stage64(As, linv + (size_t)((2*m+1)*64)*MM + (2*m+1)*64, MM, t);
    __syncthreads();
    float o[4][4]={};
    tile_gemm_step(o, As, Bs, tx, ty);
    #pragma unroll
    for (int u=0;u<4;++u)
      *(float4*)&linv[(size_t)((2*m+1)*64+ty*4+u)*MM + (2*m)*64 + tx*4] =
          make_float4(-o[u][0],-o[u][1],-o[u][2],-o[u][3]);
  }
  gbar_h(bar, xcc, myN, nxcd, gen);

  // level 1 fused per-m (one block does GEMM1+GEMM2 for its m; P via ptmp)
  for (int m=bid; m<8; m+=GRIDN){
    float* pm = ptmp + (size_t)m*128*128;
    for (int ti=0; ti<2; ++ti)
      for (int tj=0; tj<2; ++tj){
        int rb = m*4 + 2 + ti, cb0 = m*4;
        float acc[4][4]={};
        for (int k=tj; k<2; ++k){
          __syncthreads();
          stage64(As, ltri + (size_t)(rb*64)*MM + (cb0+k)*64, MM, t);
          stage64(Bs, linv + (size_t)((cb0+k)*64)*MM + (cb0+tj)*64, MM, t);
          __syncthreads();
          tile_gemm_step(acc, As, Bs, tx, ty);
        }
        #pragma unroll
        for (int u=0;u<4;++u)
          *(float4*)&pm[(size_t)(ti*64+ty*4+u)*128 + tj*64 + tx*4] =
              make_float4(acc[u][0],acc[u][1],acc[u][2],acc[u][3]);
      }
    for (int ti=0; ti<2; ++ti)
      for (int tj=0; tj<2; ++tj){
        int rb = m*4 + 2 + ti;
        float acc[4][4]={};
        for (int k=0; k<=ti; ++k){
          __syncthreads();
          stage64(As, linv + (size_t)(rb*64)*MM + (m*4+2+k)*64, MM, t);
          stage64(Bs, pm + (size_t)(k*64)*128 + tj*64, 128, t);
          __syncthreads();
          tile_gemm_step(acc, As, Bs, tx, ty);
        }
        #pragma unroll
        for (int u=0;u<4;++u)
          *(float4*)&linv[(size_t)(rb*64+ty*4+u)*MM + (m*4+tj)*64 + tx*4] =
              make_float4(-acc[u][0],-acc[u][1],-acc[u][2],-acc[u][3]);
      }
  }
  gbar_h(bar, xcc, myN, nxcd, gen);

  // levels 2..4 (two phases each)
  for (int s=2; s<5; ++s){
    int nb = 1<<s, mc = 16>>s, b = 64<<s;
    int tiles = mc*nb*nb;
    for (int idx=bid; idx<tiles; idx+=GRIDN){
      int m = idx/(nb*nb), r2 = idx%(nb*nb);
      int ti = r2/nb, tj = r2%nb;
      int rb = m*2*nb + nb + ti, cb0 = m*2*nb;
      float acc[4][4]={};
      for (int k=tj; k<nb; ++k){
        __syncthreads();
        stage64(As, ltri + (size_t)(rb*64)*MM + (cb0+k)*64, MM, t);
        stage64(Bs, linv + (size_t)((cb0+k)*64)*MM + (cb0+tj)*64, MM, t);
        __syncthreads();
        tile_gemm_step(acc, As, Bs, tx, ty);
      }
      float* pm = ptmp + (size_t)m*b*b;
      #pragma unroll
      for (int u=0;u<4;++u)
        *(float4*)&pm[(size_t)(ti*64+ty*4+u)*b + tj*64 + tx*4] =
            make_float4(acc[u][0],acc[u][1],acc[u][2],acc[u][3]);
    }
    gbar_h(bar, xcc, myN, nxcd, gen);
    for (int idx=bid; idx<tiles; idx+=GRIDN){
      int m = idx/(nb*nb), r2 = idx%(nb*nb);
      int ti = r2/nb, tj = r2%nb;
      int rb = m*2*nb + nb + ti;
      const float* pm = ptmp + (size_t)m*b*b;
      float acc[4][4]={};
      for (int k=0; k<=ti; ++k){
        __syncthreads();
        stage64(As, linv + (size_t)(rb*64)*MM + (m*2*nb+nb+k)*64, MM, t);
        stage64(Bs, pm + (size_t)(k*64)*b + tj*64, b, t);
        __syncthreads();
        tile_gemm_step(acc, As, Bs, tx, ty);
      }
      #pragma unroll
      for (int u=0;u<4;++u)
        *(float4*)&linv[(size_t)(rb*64+ty*4+u)*MM + (m*2*nb+tj)*64 + tx*4] =
            make_float4(-acc[u][0],-acc[u][1],-acc[u][2],-acc[u][3]);
    }
    gbar_h(bar, xcc, myN, nxcd, gen);
  }

  // ---- phase 4: W = Linv @ tril(qL) (both GPs), then alpha = Linv @ qm ----
  for (int idx=bid; idx<2*528; idx+=GRIDN){
    int gp = idx/528, rem = idx%528;
    int bi=0; while ((bi+1)*(bi+2)/2 <= rem) ++bi;
    int bj = rem - bi*(bi+1)/2;
    const float* ql = gp ? qlg : qlf;
    float* w        = gp ? wg  : wf;
    float acc[4][4]={};
    for (int bk=bj; bk<=bi; ++bk){
      __syncthreads();
      stage64(As, linv + (size_t)(bi*64)*MM + bk*64, MM, t);
      stage64(Bs, ql   + (size_t)(bk*64)*MM + bj*64, MM, t);
      __syncthreads();
      if (bk==bj){
        for (int p=t;p<4096;p+=256){ int i=p>>6, c=p&63; if (i<c) Bs[i][c]=0.f; }
        __syncthreads();
      }
      tile_gemm_step(acc, As, Bs, tx, ty);
    }
    #pragma unroll
    for (int u=0;u<4;++u)
      *(float4*)&w[(size_t)(bi*64+ty*4+u)*MM + bj*64 + tx*4] =
          make_float4(acc[u][0],acc[u][1],acc[u][2],acc[u][3]);
  }
  {
    int gw = bid*4 + (t>>6), l = t&63;
    for (int job=gw; job<4096; job+=GRIDN*4){
      int gp = job>>11, r = job&2047;
      const float* qm = gp ? qmg : qmf;
      float s=0.f;
      for (int c=l; c<=r; c+=64) s += linv[(size_t)r*MM+c]*qm[c];
      #pragma unroll
      for (int off=32; off; off>>=1) s += __shfl_down(s, off, 64);
      if (l==0) (gp ? ag : af)[r] = s;
    }
  }
}

// ================= small kernels (pre/post) =================

__global__ __launch_bounds__(256) void zfrag_kernel(const float* __restrict__ z,
    short* __restrict__ zfh, short* __restrict__ zfl, float* __restrict__ zn2){
  int zr = blockIdx.x*256 + threadIdx.x;
  float v[DD]; float s = 0.f;
  #pragma unroll
  for (int d=0; d<DD; ++d){ v[d] = z[zr*DD + d]; s += v[d]*v[d]; }
  zn2[zr] = s;
  size_t base = (size_t)(zr >> 4)*512 + (zr & 15)*32;
  #pragma unroll
  for (int k=0; k<32; ++k){
    short h = 0, lo = 0;
    if (k < DD) bfsplit(v[k], h, lo);
    zfh[base + k] = h; zfl[base + k] = lo;
  }
}

__global__ __launch_bounds__(256) void red_small(const float* __restrict__ lkd,
    const float* __restrict__ qlf, const float* __restrict__ qlg,
    const float* __restrict__ af, const float* __restrict__ ag,
    float* __restrict__ scal){
  __shared__ float scratch[4];
  float ldk=0, ldf=0, ldg=0, a2f=0, a2g=0;
  for (int i=threadIdx.x;i<MM;i+=256){
    int kb = i>>6, r = i&63;
    ldk += __logf(lkd[kb*4096 + r*64 + r]);
    ldf += __logf(fabsf(qlf[(size_t)i*MM+i]));
    ldg += __logf(fabsf(qlg[(size_t)i*MM+i]));
    float v = af[i]; a2f += v*v;
    v = ag[i];       a2g += v*v;
  }
  float r;
  r = block_reduce(ldk, scratch); if (threadIdx.x==0) scal[0] = 2.f*r;
  r = block_reduce(ldf, scratch); if (threadIdx.x==0) scal[1] = 2.f*r;
  r = block_reduce(ldg, scratch); if (threadIdx.x==0) scal[2] = 2.f*r;
  r = block_reduce(a2f, scratch); if (threadIdx.x==0) scal[3] = r;
  r = block_reduce(a2g, scratch); if (threadIdx.x==0) scal[4] = r;
}

__global__ __launch_bounds__(256) void redw_kernel(const float* __restrict__ wf,
    const float* __restrict__ wg, float* __restrict__ scal){
  __shared__ float scratch[4];
  size_t start  = (size_t)blockIdx.x*256 + threadIdx.x;
  size_t stride = (size_t)gridDim.x*256;
  float sf=0, sg=0;
  for (size_t p=start;p<(size_t)MM*MM;p+=stride){
    float v=wf[p]; sf += v*v;
    v=wg[p];       sg += v*v;
  }
  float r = block_reduce(sf, scratch);
  if (threadIdx.x==0) atomicAdd(&scal[5], r);
  r = block_reduce(sg, scratch);
  if (threadIdx.x==0) atomicAdd(&scal[6], r);
}

__global__ void kl_kernel(const float* __restrict__ scal, float* __restrict__ out){
  float klf = 0.5f*(scal[5] + scal[3] - (float)MM + scal[0] - scal[1]);
  float klg = 0.5f*(scal[6] + scal[4] - (float)MM + scal[0] - scal[2]);
  out[0] += klf + klg;
}

__global__ __launch_bounds__(256) void split_rowmajor(const float* __restrict__ src,
    short* __restrict__ dh, short* __restrict__ dl){
  int p = blockIdx.x*256 + threadIdx.x;
  int chunk = p >> 9, wi = p & 511;
  int mo = chunk >> 6, ko = chunk & 63;
  int row = mo*16 + (wi >> 5), col = ko*32 + (wi & 31);
  float v = src[(size_t)row*MM + col];
  short h, lo; bfsplit(v, h, lo);
  dh[p] = h; dl[p] = lo;
}

__global__ __launch_bounds__(256) void split_transpose(const float* __restrict__ src,
    short* __restrict__ dh, short* __restrict__ dl){
  __shared__ float tile[32][33];
  int t = threadIdx.x;
  int mb = blockIdx.x, kb = blockIdx.y;
  #pragma unroll
  for (int k=0;k<4;++k){
    int idx = t + k*256;
    int lr = idx >> 5, lc = idx & 31;
    tile[lr][lc] = src[(size_t)(kb*32+lr)*MM + mb*32 + lc];
  }
  __syncthreads();
  #pragma unroll
  for (int e=0;e<4;++e){
    int p = t*4 + e;
    int c = p >> 9, wi = p & 511;
    int i = (wi >> 5) & 15, kk = wi & 31;
    float v = tile[kk][c*16 + i];
    short h, lo; bfsplit(v, h, lo);
    size_t gp = ((size_t)(mb*2 + c)*64 + kb)*512 + wi;
    dh[gp] = h; dl[gp] = lo;
  }
}

__global__ __launch_bounds__(256, 2) void tt_mfma(
    const float* __restrict__ x, const float* __restrict__ zn2,
    const short* __restrict__ zfh, const short* __restrict__ zfl,
    const short* __restrict__ lvh, const short* __restrict__ lvl,
    short* __restrict__ tth, short* __restrict__ ttl){
  __shared__ __align__(16) short lAh[8192], lAl[8192], lBh[8192], lBl[8192];
  int t = threadIdx.x;
  int l = t & 63, w = t >> 6;
  int istrip = blockIdx.x, bj2 = blockIdx.y;
  int li = l & 15, q = l >> 4;
  int lofs = li*32 + q*8;
  int wn4 = (w>>1)*4, wm4 = (w&1)*4;

  short8 xh[2], xl[2];
  float xn2v[8];
  {
    float xn2t[2];
    #pragma unroll
    for (int tn=0; tn<2; ++tn){
      int n = istrip*128 + w*32 + tn*16 + li;
      const float4* xp = (const float4*)(x + (size_t)n*DD);
      float4 p0 = xp[0], p1 = xp[1];
      float v[8] = {p0.x,p0.y,p0.z,p0.w,p1.x,p1.y,p1.z,p1.w};
      float s = 0.f;
      #pragma unroll
      for (int d=0; d<8; ++d) s += v[d]*v[d];
      xn2t[tn] = s;
      short8 hh, ll;
      #pragma unroll
      for (int j=0; j<8; ++j){
        short h=0, lo=0;
        if (q==0) bfsplit(v[j], h, lo);
        hh[j]=h; ll[j]=lo;
      }
      xh[tn]=hh; xl[tn]=ll;
    }
    #pragma unroll
    for (int tn=0; tn<2; ++tn)
      #pragma unroll
      for (int r=0; r<4; ++r)
        xn2v[tn*4+r] = __shfl(xn2t[tn], q*4 + r, 64);
  }

  float4v acc[4][4];
  #pragma unroll
  for (int i=0;i<4;++i)
    #pragma unroll
    for (int j=0;j<4;++j) acc[i][j] = f4zero();

  int nkt = 2*bj2 + 2;
  for (int bk=0; bk<nkt; ++bk){
    __syncthreads();
    {
      short8 zh[4], zl[4];
      float zt2[4];
      #pragma unroll
      for (int tz=0; tz<4; ++tz){
        size_t zo = (size_t)(bk*4 + tz)*512 + lofs;
        zh[tz] = *(const short8*)(zfh + zo);
        zl[tz] = *(const short8*)(zfl + zo);
        zt2[tz] = zn2[bk*64 + tz*16 + li];
      }
      #pragma unroll
      for (int tn=0; tn<2; ++tn){
        #pragma unroll
        for (int tz=0; tz<4; ++tz){
          float4v s4 = mfma3(xh[tn], xl[tn], zh[tz], zl[tz], f4zero());
          #pragma unroll
          for (int r=0; r<4; ++r){
            float e = __expf(4.f*s4[r] - 2.f*(xn2v[tn*4+r] + zt2[tz]));
            short h, lo; bfsplit(e, h, lo);
            int pos = ((w*2+tn)*2 + (tz>>1))*512 + (q*4+r)*32 + (tz&1)*16 + li;
            lAh[pos] = h; lAl[pos] = lo;
          }
        }
      }
    }
    #pragma unroll
    for (int c4 = t; c4 < 1024; c4 += 256){
      int ch = c4 >> 6, wdi = c4 & 63;
      size_t g = ((size_t)(bj2*8 + (ch>>1))*64 + (size_t)(bk*2 + (ch&1)))*64 + wdi;
      ((uint4*)lBh)[c4] = ((const uint4*)lvh)[g];
      ((uint4*)lBl)[c4] = ((const uint4*)lvl)[g];
    }
    __syncthreads();
    #pragma unroll
    for (int s=0; s<2; ++s){
      short8 ah[4], al[4], bh[4], bl[4];
      #pragma unroll
      for (int tn=0; tn<4; ++tn){
        int off = ((wn4+tn)*2 + s)*512 + lofs;
        ah[tn] = *(const short8*)&lAh[off];
        al[tn] = *(const short8*)&lAl[off];
      }
      #pragma unroll
      for (int tm=0; tm<4; ++tm){
        int off = ((wm4+tm)*2 + s)*512 + lofs;
        bh[tm] = *(const short8*)&lBh[off];
        bl[tm] = *(const short8*)&lBl[off];
      }
      #pragma unroll
      for (int tn=0; tn<4; ++tn)
        #pragma unroll
        for (int tm=0; tm<4; ++tm)
          acc[tn][tm] = mfma3(ah[tn], al[tn], bh[tm], bl[tm], acc[tn][tm]);
    }
  }
  #pragma unroll
  for (int tn=0; tn<4; ++tn){
    int no_g = istrip*8 + wn4 + tn;
    #pragma unroll
    for (int tm=0; tm<4; ++tm){
      int mo_g = bj2*4 + (w&1)*2 + (tm>>1);
      size_t cb = ((size_t)no_g*64 + mo_g)*512;
      #pragma unroll
      for (int r=0; r<4; ++r){
        short h, lo; bfsplit(acc[tn][tm][r], h, lo);
        size_t pos = cb + (q*4+r)*32 + (tm&1)*16 + li;
        tth[pos] = h; ttl[pos] = lo;
      }
    }
  }
}

__global__ __launch_bounds__(256) void lin_v2(const short* __restrict__ tth,
    const short* __restrict__ ttl, const float* __restrict__ af, const float* __restrict__ ag,
    float* __restrict__ t2, float* __restrict__ lf, float* __restrict__ lg){
  int t = threadIdx.x;
  int w = t >> 6, l = t & 63;
  int n = blockIdx.x*4 + w;
  int g = l >> 2, j = l & 3;
  float s2=0.f, sf=0.f, sg=0.f;
  #pragma unroll
  for (int it=0; it<4; ++it){
    int ck = g + it*16;
    size_t off = ((size_t)(n>>4)*64 + ck)*512 + (n&15)*32 + j*8;
    short8 h8 = *(const short8*)(tth + off);
    short8 l8 = *(const short8*)(ttl + off);
    int m0 = ck*32 + j*8;
    float4 a0 = *(const float4*)(af + m0), a1 = *(const float4*)(af + m0 + 4);
    float4 g0 = *(const float4*)(ag + m0), g1 = *(const float4*)(ag + m0 + 4);
    float av[8] = {a0.x,a0.y,a0.z,a0.w,a1.x,a1.y,a1.z,a1.w};
    float gv[8] = {g0.x,g0.y,g0.z,g0.w,g1.x,g1.y,g1.z,g1.w};
    #pragma unroll
    for (int e=0; e<8; ++e){
      float tv = bf2f(h8[e]) + bf2f(l8[e]);
      s2 += tv*tv; sf += tv*av[e]; sg += tv*gv[e];
    }
  }
  #pragma unroll
  for (int off=32; off; off>>=1){
    s2 += __shfl_down(s2, off, 64);
    sf += __shfl_down(sf, off, 64);
    sg += __shfl_down(sg, off, 64);
  }
  if (l==0){ t2[n] = s2; lf[n] = sf; lg[n] = sg; }
}

__global__ __launch_bounds__(256, 2) void quad_mfma(
    const short* __restrict__ tth, const short* __restrict__ ttl,
    const short* __restrict__ wfh, const short* __restrict__ wfl,
    const short* __restrict__ wgh, const short* __restrict__ wgl,
    float* __restrict__ vfq, float* __restrict__ vgq){
  __shared__ __align__(16) short lAh[8192], lAl[8192], lBh[8192], lBl[8192];
  int t = threadIdx.x, l = t & 63, w = t >> 6;
  int istrip = blockIdx.x, bj2 = blockIdx.y;
  const short* gbh = blockIdx.z ? wgh : wfh;
  const short* gbl = blockIdx.z ? wgl : wfl;
  float* vq = blockIdx.z ? vgq : vfq;
  int li = l & 15, q = l >> 4;
  int lofs = li*32 + q*8;
  int wn4 = (w>>1)*4, wm4 = (w&1)*4;

  float4v acc[4][4];
  #pragma unroll
  for (int i=0;i<4;++i)
    #pragma unroll
    for (int j=0;j<4;++j) acc[i][j] = f4zero();

  for (int bk=2*bj2; bk<32; ++bk){
    __syncthreads();
    #pragma unroll
    for (int c4 = t; c4 < 1024; c4 += 256){
      int ch = c4 >> 6, wdi = c4 & 63;
      size_t ga = ((size_t)(istrip*8 + (ch>>1))*64 + (size_t)(bk*2 + (ch&1)))*64 + wdi;
      ((uint4*)lAh)[c4] = ((const uint4*)tth)[ga];
      ((uint4*)lAl)[c4] = ((const uint4*)ttl)[ga];
      size_t gb = ((size_t)(bj2*8 + (ch>>1))*64 + (size_t)(bk*2 + (ch&1)))*64 + wdi;
      ((uint4*)lBh)[c4] = ((const uint4*)gbh)[gb];
      ((uint4*)lBl)[c4] = ((const uint4*)gbl)[gb];
    }
    __syncthreads();
    #pragma unroll
    for (int s=0; s<2; ++s){
      short8 ah[4], al[4], bh[4], bl[4];
      #pragma unroll
      for (int tn=0; tn<4; ++tn){
        int off = ((wn4+tn)*2 + s)*512 + lofs;
        ah[tn] = *(const short8*)&lAh[off];
        al[tn] = *(const short8*)&lAl[off];
      }
      #pragma unroll
      for (int tm=0; tm<4; ++tm){
        int off = ((wm4+tm)*2 + s)*512 + lofs;
        bh[tm] = *(const short8*)&lBh[off];
        bl[tm] = *(const short8*)&lBl[off];
      }
      #pragma unroll
      for (int tn=0; tn<4; ++tn)
        #pragma unroll
        for (int tm=0; tm<4; ++tm)
          acc[tn][tm] = mfma3(ah[tn], al[tn], bh[tm], bl[tm], acc[tn][tm]);
    }
  }
  float rs[16];
  #pragma unroll
  for (int tn=0; tn<4; ++tn)
    #pragma unroll
    for (int r=0; r<4; ++r){
      float s = 0.f;
      #pragma unroll
      for (int tm=0; tm<4; ++tm){ float v = acc[tn][tm][r]; s += v*v; }
      rs[tn*4+r] = s;
    }
  #pragma unroll
  for (int off=8; off; off>>=1)
    #pragma unroll
    for (int k=0; k<16; ++k) rs[k] += __shfl_down(rs[k], off, 16);
  if (li == 0){
    #pragma unroll
    for (int tn=0; tn<4; ++tn)
      #pragma unroll
      for (int r=0; r<4; ++r){
        int n = istrip*128 + (w>>1)*64 + tn*16 + q*4 + r;
        atomicAdd(&vq[n], rs[tn*4+r]);
      }
  }
}

__global__ __launch_bounds__(256) void final_kernel(const float* __restrict__ y,
    const float* __restrict__ t2, const float* __restrict__ lf, const float* __restrict__ lg,
    const float* __restrict__ vfq, const float* __restrict__ vgq, float* __restrict__ out){
  __shared__ float scratch[4];
  int i = blockIdx.x*256 + threadIdx.x;
  float mf = lf[i], mg = lg[i];
  float vf = 1.f + vfq[i] - t2[i];
  float vg = 1.f + vgq[i] - t2[i];
  float dy = y[i] - mf;
  float e = -HLOG2PI - 0.5f*mg - 0.5f*(dy*dy + vf)*__expf(-mg + 0.5f*vg);
  float r = block_reduce(e, scratch);
  if (threadIdx.x==0) atomicAdd(out, -r);
}

extern "C" void kernel_launch(void* const* d_in, const int* in_sizes, int n_in,
                              void* d_out, int out_size, void* d_ws, size_t ws_size,
                              hipStream_t stream){
  (void)in_sizes; (void)n_in; (void)out_size; (void)ws_size;
  const float* x   = (const float*)d_in[0];
  const float* y   = (const float*)d_in[1];
  const float* z   = (const float*)d_in[2];
  const float* qmf = (const float*)d_in[3];
  const float* qlf = (const float*)d_in[4];
  const float* qmg = (const float*)d_in[5];
  const float* qlg = (const float*)d_in[6];
  float* out = (float*)d_out;
  char* Bw = (char*)d_ws;

  float* kuu  = (float*)Bw;
  float* linv = (float*)(Bw + SZB);
  float* wf   = (float*)(Bw + 2*SZB);
  float* wg   = (float*)(Bw + 3*SZB);
  short* lvh  = (short*)Bw;
  short* lvl  = (short*)(Bw + SZB/2);
  short* wfh  = (short*)(Bw + SZB);
  short* wfl  = (short*)(Bw + SZB + SZB/2);
  short* wgh  = (short*)(Bw + 2*SZB);
  short* wgl  = (short*)(Bw + 2*SZB + SZB/2);
  short* tth  = (short*)(Bw + 3*SZB);
  short* ttl  = (short*)(Bw + 3*SZB + (size_t)NN*MM*2);
  // dead-tt region [64M,112M): ltri 16MB, ptmp 4MB, lkdiag 512KB, sdg 8KB
  float* ltri   = (float*)(Bw + 4*SZB);
  float* ptmp   = (float*)(Bw + 5*SZB);
  float* lkdiag = (float*)(Bw + 5*SZB + (size_t)4194304);
  float* sdg    = (float*)(Bw + 5*SZB + (size_t)4194304 + (size_t)524288);
  float* sm   = (float*)(Bw + 3*SZB + (size_t)NN*MM*4);
  float* af = sm;          float* ag = af + MM;
  float* t2 = ag + MM;     float* lf = t2 + NN;   float* lg = lf + NN;
  float* vfq = lg + NN;    float* vgq = vfq + NN; float* scal = vgq + NN;
  int*   bar = (int*)(scal + 64);    // 2048 ints of barrier state (zeroed)
  float* zn2 = scal + 64 + 2048;
  short* zfh = (short*)(zn2 + MM);
  short* zfl = zfh + MM*32;

  hipMemsetAsync(out, 0, sizeof(float), stream);
  hipMemsetAsync(vfq, 0, (size_t)(2*NN + 64 + 2048)*sizeof(float), stream); // vfq,vgq,scal,bar
  hipMemsetAsync(wf,  0, 2*SZB, stream);    // W upper triangles must be 0
  hipMemsetAsync(linv,0, SZB,   stream);    // Linv upper must be 0

  zfrag_kernel<<<MM/256, 256, 0, stream>>>(z, zfh, zfl, zn2);

  factor_coop<<<GRIDN, 256, 0, stream>>>(z, qlf, qlg, qmf, qmg,
                                         kuu, linv, wf, wg, af, ag,
                                         ptmp, lkdiag, sdg, ltri, bar);

  red_small<<<1, 256, 0, stream>>>(lkdiag, qlf, qlg, af, ag, scal);
  redw_kernel<<<512, 256, 0, stream>>>(wf, wg, scal);
  kl_kernel<<<1, 1, 0, stream>>>(scal, out);

  split_rowmajor<<<MM*MM/256, 256, 0, stream>>>(linv, lvh, lvl);
  split_transpose<<<dim3(MM/32, MM/32), 256, 0, stream>>>(wf, wfh, wfl);
  split_transpose<<<dim3(MM/32, MM/32), 256, 0, stream>>>(wg, wgh, wgl);

  tt_mfma<<<dim3(NN/128, MM/128), 256, 0, stream>>>(x, zn2, zfh, zfl, lvh, lvl, tth, ttl);
  lin_v2<<<NN/4, 256, 0, stream>>>(tth, ttl, af, ag, t2, lf, lg);
  quad_mfma<<<dim3(NN/128, MM/128, 2), 256, 0, stream>>>(tth, ttl, wfh, wfl, wgh, wgl, vfq, vgq);
  final_kernel<<<NN/256, 256, 0, stream>>>(y, t2, lf, lg, vfq, vgq, out);
}